// Round 2
// baseline (413.932 us; speedup 1.0000x reference)
//
#include <hip/hip_runtime.h>

// Problem constants (SVGA_7318624272625)
#define N_NODES 50000
#define N_EDGES 800000
#define F_IN    256
#define H_DIM   64
#define NB_SCAN ((N_NODES + 255) / 256)   // 196 dst buckets (256 nodes each)
#define TILE_A  4096                       // edges per binA block -> 196 blocks
#define EPT     (TILE_A / 256)             // edges per thread in binA (16)
#define MAXB    5632                       // max edges per bucket (avg 4081, +24 sigma)
#define GT1     ((N_NODES + 63) / 64)      // gemm1 tile blocks (782)
#define DEC_BLOCKS 1568

typedef __attribute__((ext_vector_type(8))) short short8;
typedef __attribute__((ext_vector_type(4))) float floatx4;

__device__ __forceinline__ unsigned short f2bf(float f) {  // RNE fp32->bf16
  unsigned int u;
  __builtin_memcpy(&u, &f, 4);
  u += 0x7fffu + ((u >> 16) & 1u);
  return (unsigned short)(u >> 16);
}
__device__ __forceinline__ float bf2f(unsigned short s) {
  unsigned int v = ((unsigned int)s) << 16; float f; __builtin_memcpy(&f, &v, 4); return f;
}

// Pack helper: W[K,64] (fp32) -> bf16 MFMA B-fragments, frag id
// f = (ks*4+c)*2+m ; lane L, j holds B[k=ks*32+(L>>4)*8+j][n=c*16+(L&15)].
template<int K>
__device__ __forceinline__ void pack_body(int t, const float* __restrict__ Wl,
                                          const float* __restrict__ Wr,
                                          unsigned short* __restrict__ Wb)
{
  int lane = t & 63;
  int f    = t >> 6;
  int m    = f & 1;
  int c    = (f >> 1) & 3;
  int ks   = f >> 3;
  const float* W = m ? Wr : Wl;
  int quad = lane >> 4, l15 = lane & 15;
  int col = c * 16 + l15;
  unsigned short u[8];
#pragma unroll
  for (int j = 0; j < 8; ++j) {
    int k = ks * 32 + quad * 8 + j;
    u[j] = f2bf(W[k * H_DIM + col]);
  }
  uint4 v;
  __builtin_memcpy(&v, u, 16);
  ((uint4*)Wb)[t] = v;
}

// Fused pack: blocks 0-15 pack W1 (4096 frags*lanes), 16-19 pack W2 (1024);
// block 0 also zeroes the loss slot and the bucket cursors (binA runs in a
// LATER dispatch on the same stream, so this ordering is safe).
__global__ __launch_bounds__(256) void pack_all_k(
    const float* __restrict__ W1l, const float* __restrict__ W1r,
    const float* __restrict__ W2l, const float* __restrict__ W2r,
    unsigned short* __restrict__ Wb1, unsigned short* __restrict__ Wb2,
    float* __restrict__ loss_slot, int* __restrict__ bcur)
{
  if (blockIdx.x == 0) {
    if (threadIdx.x == 0) loss_slot[0] = 0.f;
    if (threadIdx.x < NB_SCAN) bcur[threadIdx.x] = 0;
  }
  int b = blockIdx.x;
  if (b < 16) {
    pack_body<F_IN>(b * 256 + threadIdx.x, W1l, W1r, Wb1);
  } else {
    pack_body<H_DIM>((b - 16) * 256 + threadIdx.x, W2l, W2r, Wb2);
  }
}

// MFMA dual-GEMM body: outl = bf16(X@Wl + bl), outr = bf16(X@Wr).
// xs must point at >= 64*(K+8) ushorts of LDS (16B aligned).
template<int K, bool XBF16>
__device__ __forceinline__ void gemm_body(
    int bx, unsigned short* xs,
    const void* __restrict__ X_,
    const unsigned short* __restrict__ Wb,
    const float* __restrict__ bl,
    unsigned short* __restrict__ outl, unsigned short* __restrict__ outr)
{
  constexpr int KP = K + 8;                 // padded row length (bf16 units)
  const int row0 = bx * 64;
  if (XBF16) {
    const uint4* X = (const uint4*)X_;      // row = K bf16 = K/8 uint4
    const int CH = K / 8;
    for (int i = threadIdx.x; i < 64 * CH; i += 256) {
      int r = i / CH, c = i % CH;
      int row = row0 + r;
      uint4 v = (row < N_NODES) ? X[(size_t)row * CH + c] : make_uint4(0, 0, 0, 0);
      *(uint4*)&xs[r * KP + c * 8] = v;
    }
  } else {
    const float4* X = (const float4*)X_;
    const int CH = K / 4;
    for (int i = threadIdx.x; i < 64 * CH; i += 256) {
      int r = i / CH, c = i % CH;
      int row = row0 + r;
      float4 v = (row < N_NODES) ? X[(size_t)row * CH + c]
                                 : make_float4(0.f, 0.f, 0.f, 0.f);
      unsigned int lo = (unsigned int)f2bf(v.x) | ((unsigned int)f2bf(v.y) << 16);
      unsigned int hi = (unsigned int)f2bf(v.z) | ((unsigned int)f2bf(v.w) << 16);
      *(uint2*)&xs[r * KP + c * 4] = make_uint2(lo, hi);
    }
  }
  __syncthreads();

  const int lane = threadIdx.x & 63;
  const int w    = threadIdx.x >> 6;
  const int quad = lane >> 4;
  const int l15  = lane & 15;
  const int rloc = w * 16 + l15;            // A-frag row

  floatx4 accl[4], accr[4];
#pragma unroll
  for (int c = 0; c < 4; ++c) { accl[c] = (floatx4)0.f; accr[c] = (floatx4)0.f; }

  const uint4* wbase = (const uint4*)Wb;
#pragma unroll
  for (int ks = 0; ks < K / 32; ++ks) {
    short8 af = *(const short8*)&xs[rloc * KP + ks * 32 + quad * 8];
#pragma unroll
    for (int c = 0; c < 4; ++c) {
      uint4 rl = wbase[((ks * 4 + c) * 2 + 0) * 64 + lane];
      uint4 rr = wbase[((ks * 4 + c) * 2 + 1) * 64 + lane];
      short8 bfl, bfr;
      __builtin_memcpy(&bfl, &rl, 16);
      __builtin_memcpy(&bfr, &rr, 16);
      accl[c] = __builtin_amdgcn_mfma_f32_16x16x32_bf16(af, bfl, accl[c], 0, 0, 0);
      accr[c] = __builtin_amdgcn_mfma_f32_16x16x32_bf16(af, bfr, accr[c], 0, 0, 0);
    }
  }
#pragma unroll
  for (int c = 0; c < 4; ++c) {
    int col = c * 16 + l15;
    float bias = bl[col];
#pragma unroll
    for (int reg = 0; reg < 4; ++reg) {
      int row = row0 + w * 16 + quad * 4 + reg;
      if (row < N_NODES) {
        outl[(size_t)row * H_DIM + col] = f2bf(accl[c][reg] + bias);
        outr[(size_t)row * H_DIM + col] = f2bf(accr[c][reg]);
      }
    }
  }
}

// binA: LDS-binned bucket scatter into fixed-stride bucket regions
// (ebuf[b*MAXB + cursor]); one global atomic per (block,bucket).
// bcur zeroed by pack_all_k (previous dispatch). ei read exactly once.
__global__ __launch_bounds__(256) void binA_k(const int* __restrict__ ei,
                                              int* __restrict__ bcur,
                                              unsigned int* __restrict__ ebuf)
{
  __shared__ int lcnt[256];
  __shared__ int lofs[256];
  __shared__ int lstart[256];
  __shared__ int gstart[256];
  __shared__ int lcur[256];
  __shared__ unsigned int ldata[TILE_A];   // 16 KB
  const int t = threadIdx.x;
  const int e0 = blockIdx.x * TILE_A;
  lcnt[t] = 0;
  __syncthreads();
  int ss[EPT], ds[EPT];
#pragma unroll
  for (int j = 0; j < EPT; ++j) {
    int e = e0 + t + j * 256;              // coalesced
    if (e < N_EDGES) {
      ss[j] = ei[e];
      ds[j] = ei[N_EDGES + e];
      atomicAdd(&lcnt[ds[j] >> 8], 1);
    } else {
      ds[j] = -1;
    }
  }
  __syncthreads();
  int v = lcnt[t];
  lofs[t] = v;
  __syncthreads();
  for (int off = 1; off < 256; off <<= 1) {
    int u = (t >= off) ? lofs[t - off] : 0;
    __syncthreads();
    lofs[t] += u;
    __syncthreads();
  }
  lstart[t] = lofs[t] - v;
  lcur[t]   = lofs[t] - v;
  if (t < NB_SCAN && v > 0) gstart[t] = atomicAdd(&bcur[t], v);
  __syncthreads();
#pragma unroll
  for (int j = 0; j < EPT; ++j) {
    if (ds[j] >= 0) {
      int p = atomicAdd(&lcur[ds[j] >> 8], 1);
      ldata[p] = ((unsigned int)ss[j] << 8) | (unsigned int)(ds[j] & 255);
    }
  }
  __syncthreads();
  int w = t >> 6, lane = t & 63;
  for (int b = w; b < NB_SCAN; b += 4) {
    int st = lstart[b], len = lcnt[b];
    if (len == 0) continue;
    int g = gstart[b];
    unsigned int* dst = ebuf + (size_t)b * MAXB;
    for (int j = lane; j < len; j += 64) {
      int gp = g + j;
      if (gp < MAXB) dst[gp] = ldata[st + j];   // clamp: statistically unreachable
    }
  }
}

// binB body: fused bucket-offset scan (over bcur) + per-bucket counting sort +
// CSR finalize: writes esrc (coalesced) and rowptr.  (edst is dead: decode
// walks CSR runs directly.)  smem: 4*256 ints + 2 ints + MAXB uints = 26.6 KB.
__device__ __forceinline__ void binB_body(
    int b, unsigned char* smem,
    const unsigned int* __restrict__ ebuf, const int* __restrict__ bcur,
    int* __restrict__ esrc, int* __restrict__ rowptr)
{
  int* sc    = (int*)smem;                 // 256
  int* ncnt  = sc + 256;                   // 256
  int* nscan = ncnt + 256;                 // 256
  int* ncur  = nscan + 256;                // 256
  int* sh_se = ncur + 256;                 // 2
  unsigned int* sdata = (unsigned int*)(sh_se + 2);   // MAXB
  const int t = threadIdx.x;
  // Bucket offsets: inclusive scan over clamped bucket lengths (196 ints).
  int bl = (t < NB_SCAN) ? min(bcur[t], MAXB) : 0;
  sc[t] = bl;
  __syncthreads();
  for (int off = 1; off < 256; off <<= 1) {
    int u = (t >= off) ? sc[t - off] : 0;
    __syncthreads();
    sc[t] += u;
    __syncthreads();
  }
  if (t == b) { sh_se[0] = sc[t] - bl; sh_se[1] = bl; }
  __syncthreads();
  const int start = sh_se[0], len = sh_se[1];
  const unsigned int* eb = ebuf + (size_t)b * MAXB;
  // Per-node histogram within the bucket.
  ncnt[t] = 0;
  __syncthreads();
  for (int i = t; i < len; i += 256) atomicAdd(&ncnt[eb[i] & 255], 1);
  __syncthreads();
  int v = ncnt[t];
  nscan[t] = v;
  __syncthreads();
  for (int off = 1; off < 256; off <<= 1) {
    int u = (t >= off) ? nscan[t - off] : 0;
    __syncthreads();
    nscan[t] += u;
    __syncthreads();
  }
  ncur[t] = nscan[t] - v;
  __syncthreads();
  for (int i = t; i < len; i += 256) {
    unsigned int e = eb[i];
    int p = atomicAdd(&ncur[e & 255], 1);
    sdata[p] = e >> 8;
  }
  __syncthreads();
  for (int i = t; i < len; i += 256) esrc[start + i] = (int)sdata[i];
  // rowptr: node (b*256+t) owns [start+nscan[t]-v, start+nscan[t])
  int node = b * 256 + t;
  int s0 = start + nscan[t] - v;
  if (node < N_NODES) {
    rowptr[node] = s0;
    if (node == N_NODES - 1) rowptr[N_NODES] = s0 + v;   // == E
  }
}

// Fused independent dispatches: blocks [0,GT1) run gemm1 (depends on pack),
// blocks [GT1,GT1+196) run binB (depends on binA).  No shared data; one LDS
// buffer overlaid (gemm path 33.8 KB dominates -> 4 blocks/CU either way).
__global__ __launch_bounds__(256, 4) void binB_gemm1_k(
    const float* __restrict__ x, const unsigned short* __restrict__ Wb1,
    const float* __restrict__ b1l,
    unsigned short* __restrict__ m1, unsigned short* __restrict__ xr,
    const unsigned int* __restrict__ ebuf, const int* __restrict__ bcur,
    int* __restrict__ esrc, int* __restrict__ rowptr)
{
  __shared__ __align__(16) unsigned char smem[64 * (F_IN + 8) * 2];  // 33792 B
  if (blockIdx.x < GT1) {
    gemm_body<F_IN, false>(blockIdx.x, (unsigned short*)smem, x, Wb1, b1l, m1, xr);
  } else {
    binB_body(blockIdx.x - GT1, smem, ebuf, bcur, esrc, rowptr);
  }
}

// Layer-2 GEMM stays standalone (depends on agg1).
__global__ __launch_bounds__(256, 4) void gemm2_k(
    const void* __restrict__ X_, const unsigned short* __restrict__ Wb,
    const float* __restrict__ bl,
    unsigned short* __restrict__ outl, unsigned short* __restrict__ outr)
{
  __shared__ __align__(16) unsigned short xs[64 * (H_DIM + 8)];
  gemm_body<H_DIM, true>(blockIdx.x, xs, X_, Wb, bl, outl, outr);
}

// ---- Fused aggregation: wave per dst node, lane = feature, bf16 everywhere ----
__device__ __forceinline__ float agg_row_b(const int* __restrict__ esrc,
                                           const unsigned short* __restrict__ m,
                                           int b, int e, int lane)
{
  float a0 = 0.f, a1 = 0.f, a2 = 0.f, a3 = 0.f;
  float a4 = 0.f, a5 = 0.f, a6 = 0.f, a7 = 0.f;
  int i = b;
  for (; i + 8 <= e; i += 8) {
    int s0 = esrc[i],     s1 = esrc[i + 1], s2 = esrc[i + 2], s3 = esrc[i + 3];
    int s4 = esrc[i + 4], s5 = esrc[i + 5], s6 = esrc[i + 6], s7 = esrc[i + 7];
    a0 += bf2f(m[(size_t)s0 * H_DIM + lane]);
    a1 += bf2f(m[(size_t)s1 * H_DIM + lane]);
    a2 += bf2f(m[(size_t)s2 * H_DIM + lane]);
    a3 += bf2f(m[(size_t)s3 * H_DIM + lane]);
    a4 += bf2f(m[(size_t)s4 * H_DIM + lane]);
    a5 += bf2f(m[(size_t)s5 * H_DIM + lane]);
    a6 += bf2f(m[(size_t)s6 * H_DIM + lane]);
    a7 += bf2f(m[(size_t)s7 * H_DIM + lane]);
  }
  for (; i + 4 <= e; i += 4) {
    int s0 = esrc[i], s1 = esrc[i + 1], s2 = esrc[i + 2], s3 = esrc[i + 3];
    a0 += bf2f(m[(size_t)s0 * H_DIM + lane]);
    a1 += bf2f(m[(size_t)s1 * H_DIM + lane]);
    a2 += bf2f(m[(size_t)s2 * H_DIM + lane]);
    a3 += bf2f(m[(size_t)s3 * H_DIM + lane]);
  }
  for (; i < e; ++i) a0 += bf2f(m[(size_t)esrc[i] * H_DIM + lane]);
  return ((a0 + a1) + (a2 + a3)) + ((a4 + a5) + (a6 + a7));
}

// h = relu(mean m1 + xr) -> bf16
__global__ __launch_bounds__(256) void agg1_k(
    const int* __restrict__ rowptr, const int* __restrict__ esrc,
    const unsigned short* __restrict__ m, const unsigned short* __restrict__ xr,
    unsigned short* __restrict__ h)
{
  int gid = blockIdx.x * 256 + threadIdx.x;
  int row = gid >> 6, lane = gid & 63;
  if (row >= N_NODES) return;
  int b = rowptr[row], e = rowptr[row + 1];
  float acc = agg_row_b(esrc, m, b, e, lane);
  float dv = fmaxf((float)(e - b), 1.f);
  size_t o = (size_t)row * H_DIM + lane;
  h[o] = f2bf(fmaxf(acc / dv + bf2f(xr[o]), 0.f));
}

// z = unitnorm(mean m2 + hr) -> fp32 d_out + bf16 copy (decode gathers)
__global__ __launch_bounds__(256) void agg2_k(
    const int* __restrict__ rowptr, const int* __restrict__ esrc,
    const unsigned short* __restrict__ m, const unsigned short* __restrict__ hr,
    float* __restrict__ zout, unsigned short* __restrict__ zb)
{
  int gid = blockIdx.x * 256 + threadIdx.x;
  int row = gid >> 6, lane = gid & 63;
  if (row >= N_NODES) return;
  int b = rowptr[row], e = rowptr[row + 1];
  float acc = agg_row_b(esrc, m, b, e, lane);
  float dv = fmaxf((float)(e - b), 1.f);
  size_t o = (size_t)row * H_DIM + lane;
  float v = acc / dv + bf2f(hr[o]);
  float ss = v * v;
#pragma unroll
  for (int mm = 32; mm >= 1; mm >>= 1) ss += __shfl_xor(ss, mm, 64);
  float z = v * rsqrtf(fmaxf(ss, 1e-30f));
  zout[o] = z;
  zb[o] = f2bf(z);
}

// Decode: wave per dst node (CSR runs), lane = feature.  z_dst loaded once
// per node into registers; each edge reads one wave-coalesced 128B src row;
// score via 6-step butterfly (uniform across wave).  Grid-stride over rows.
__global__ __launch_bounds__(256) void decode_csr_k(
    const int* __restrict__ rowptr, const int* __restrict__ esrc,
    const unsigned short* __restrict__ zb, float* __restrict__ loss_slot)
{
  const int lane = threadIdx.x & 63;
  const int wid  = (blockIdx.x * 256 + threadIdx.x) >> 6;   // global wave id
  const int nw   = DEC_BLOCKS * 4;
  float part = 0.f;
  for (int row = wid; row < N_NODES; row += nw) {
    int b = rowptr[row], e = rowptr[row + 1];
    if (b == e) continue;
    float zd = bf2f(zb[(size_t)row * H_DIM + lane]);
    int i = b;
    for (; i + 2 <= e; i += 2) {
      int s0 = esrc[i], s1 = esrc[i + 1];
      float p0 = bf2f(zb[(size_t)s0 * H_DIM + lane]) * zd;
      float p1 = bf2f(zb[(size_t)s1 * H_DIM + lane]) * zd;
#pragma unroll
      for (int m = 32; m >= 1; m >>= 1) {
        p0 += __shfl_xor(p0, m, 64);
        p1 += __shfl_xor(p1, m, 64);
      }
      part += fmaxf(-p0, 0.f) + log1pf(expf(-fabsf(p0)));
      part += fmaxf(-p1, 0.f) + log1pf(expf(-fabsf(p1)));
    }
    if (i < e) {
      int s = esrc[i];
      float p = bf2f(zb[(size_t)s * H_DIM + lane]) * zd;
#pragma unroll
      for (int m = 32; m >= 1; m >>= 1) p += __shfl_xor(p, m, 64);
      part += fmaxf(-p, 0.f) + log1pf(expf(-fabsf(p)));
    }
  }
  // part is identical across the 64 lanes of a wave: one contribution per wave.
  __shared__ float sbuf[4];
  int w = threadIdx.x >> 6;
  if (lane == 0) sbuf[w] = part;
  __syncthreads();
  if (threadIdx.x == 0)
    atomicAdd(loss_slot, (sbuf[0] + sbuf[1] + sbuf[2] + sbuf[3]) * (1.0f / N_EDGES));
}

extern "C" void kernel_launch(void* const* d_in, const int* in_sizes, int n_in,
                              void* d_out, int out_size, void* d_ws, size_t ws_size,
                              hipStream_t stream)
{
  (void)in_sizes; (void)n_in; (void)out_size; (void)ws_size;
  const float* x   = (const float*)d_in[0];
  const int*   ei  = (const int*)d_in[1];
  const float* W1l = (const float*)d_in[2];
  const float* b1l = (const float*)d_in[3];
  const float* W1r = (const float*)d_in[4];
  const float* W2l = (const float*)d_in[5];
  const float* b2l = (const float*)d_in[6];
  const float* W2r = (const float*)d_in[7];
  float* out = (float*)d_out;  // fp32: z [N*H] ++ loss [1]
  float* loss_slot = out + (size_t)N_NODES * H_DIM;

  const size_t NH = (size_t)N_NODES * H_DIM;
  // uA = m1 then m2; uB = h then zb; uC = xr then hr (all bf16).
  unsigned short* uA = (unsigned short*)d_ws;   // NH ushort
  unsigned short* uB = uA + NH;                 // NH ushort
  unsigned short* uC = uB + NH;                 // NH ushort
  // Wb right after bf16 buffers: 19.2 MB offset is 16B-aligned (uint4 access).
  unsigned short* Wb1 = uC + NH;                             // 64 KB
  unsigned short* Wb2 = Wb1 + (F_IN / 32) * 4 * 2 * 64 * 8;  // 16 KB
  int* rowptr = (int*)(Wb2 + (H_DIM / 32) * 4 * 2 * 64 * 8); // N+1
  int* esrc   = rowptr + N_NODES + 1;   // E
  int* bcur   = esrc + N_EDGES;         // NB_SCAN
  unsigned int* ebuf = (unsigned int*)(bcur + NB_SCAN);      // NB_SCAN*MAXB (4.4 MB)

  dim3 blk(256);
  dim3 g_node((N_NODES * 64 + 255) / 256);
  dim3 g_binA((N_EDGES + TILE_A - 1) / TILE_A);   // 196
  dim3 g_fuse(GT1 + NB_SCAN);                     // 978
  dim3 g_tile(GT1);                               // 782
  dim3 g_dec(DEC_BLOCKS);                         // 1568

  // Pack W1+W2 fragments (bf16) + zero loss slot + zero bucket cursors
  pack_all_k<<<dim3(20), blk, 0, stream>>>(W1l, W1r, W2l, W2r, Wb1, Wb2,
                                           loss_slot, bcur);
  // CSR build stage A: LDS-binned bucket scatter
  binA_k<<<g_binA, blk, 0, stream>>>(ei, bcur, ebuf);
  // Fused: gemm1 (m1 -> uA, xr -> uC) || binB (esrc+rowptr) — independent
  binB_gemm1_k<<<g_fuse, blk, 0, stream>>>(x, Wb1, b1l, uA, uC,
                                           ebuf, bcur, esrc, rowptr);
  agg1_k<<<g_node, blk, 0, stream>>>(rowptr, esrc, uA, uC, uB);
  // Layer 2 (MFMA, bf16 input): m2 -> uA, hr -> uC (bf16)
  gemm2_k<<<g_tile, blk, 0, stream>>>(uB, Wb2, b2l, uA, uC);
  agg2_k<<<g_node, blk, 0, stream>>>(rowptr, esrc, uA, uC, out, uB);
  // Decode + loss (wave per dst run, coalesced src gathers)
  decode_csr_k<<<g_dec, blk, 0, stream>>>(rowptr, esrc, uB, loss_slot);
}

// Round 3
// 239.559 us; speedup vs baseline: 1.7279x; 1.7279x over previous
//
#include <hip/hip_runtime.h>

// Problem constants (SVGA_7318624272625)
#define N_NODES 50000
#define N_EDGES 800000
#define F_IN    256
#define H_DIM   64
#define NB_SCAN ((N_NODES + 255) / 256)   // 196 dst buckets (256 nodes each)
#define TILE_A  4096                       // edges per binA block -> 196 blocks
#define EPT     (TILE_A / 256)             // edges per thread in binA (16)
#define MAXB    5632                       // max edges per bucket (avg 4081, +24 sigma)
#define GT1     ((N_NODES + 63) / 64)      // gemm1 tile blocks (782)
#define SUBN    64                         // decode: dst nodes per block
#define DEC_GRID ((N_NODES + SUBN - 1) / SUBN)   // 782

typedef __attribute__((ext_vector_type(8))) short short8;
typedef __attribute__((ext_vector_type(4))) float floatx4;

__device__ __forceinline__ unsigned short f2bf(float f) {  // RNE fp32->bf16
  unsigned int u;
  __builtin_memcpy(&u, &f, 4);
  u += 0x7fffu + ((u >> 16) & 1u);
  return (unsigned short)(u >> 16);
}
__device__ __forceinline__ float bf2f(unsigned short s) {
  unsigned int v = ((unsigned int)s) << 16; float f; __builtin_memcpy(&f, &v, 4); return f;
}
__device__ __forceinline__ float bflo(unsigned int u) {
  unsigned int v = u << 16; float f; __builtin_memcpy(&f, &v, 4); return f;
}
__device__ __forceinline__ float bfhi(unsigned int u) {
  unsigned int v = u & 0xffff0000u; float f; __builtin_memcpy(&f, &v, 4); return f;
}

// Pack helper: W[K,64] (fp32) -> bf16 MFMA B-fragments, frag id
// f = (ks*4+c)*2+m ; lane L, j holds B[k=ks*32+(L>>4)*8+j][n=c*16+(L&15)].
template<int K>
__device__ __forceinline__ void pack_body(int t, const float* __restrict__ Wl,
                                          const float* __restrict__ Wr,
                                          unsigned short* __restrict__ Wb)
{
  int lane = t & 63;
  int f    = t >> 6;
  int m    = f & 1;
  int c    = (f >> 1) & 3;
  int ks   = f >> 3;
  const float* W = m ? Wr : Wl;
  int quad = lane >> 4, l15 = lane & 15;
  int col = c * 16 + l15;
  unsigned short u[8];
#pragma unroll
  for (int j = 0; j < 8; ++j) {
    int k = ks * 32 + quad * 8 + j;
    u[j] = f2bf(W[k * H_DIM + col]);
  }
  uint4 v;
  __builtin_memcpy(&v, u, 16);
  ((uint4*)Wb)[t] = v;
}

// Fused pack: blocks 0-15 pack W1 (4096 frags*lanes), 16-19 pack W2 (1024);
// block 0 also zeroes the loss slot and the bucket cursors (binA runs in a
// LATER dispatch on the same stream, so this ordering is safe).
__global__ __launch_bounds__(256) void pack_all_k(
    const float* __restrict__ W1l, const float* __restrict__ W1r,
    const float* __restrict__ W2l, const float* __restrict__ W2r,
    unsigned short* __restrict__ Wb1, unsigned short* __restrict__ Wb2,
    float* __restrict__ loss_slot, int* __restrict__ bcur)
{
  if (blockIdx.x == 0) {
    if (threadIdx.x == 0) loss_slot[0] = 0.f;
    if (threadIdx.x < NB_SCAN) bcur[threadIdx.x] = 0;
  }
  int b = blockIdx.x;
  if (b < 16) {
    pack_body<F_IN>(b * 256 + threadIdx.x, W1l, W1r, Wb1);
  } else {
    pack_body<H_DIM>((b - 16) * 256 + threadIdx.x, W2l, W2r, Wb2);
  }
}

// MFMA dual-GEMM body: outl = bf16(X@Wl + bl), outr = bf16(X@Wr).
// xs must point at >= 64*(K+8) ushorts of LDS (16B aligned).
template<int K, bool XBF16>
__device__ __forceinline__ void gemm_body(
    int bx, unsigned short* xs,
    const void* __restrict__ X_,
    const unsigned short* __restrict__ Wb,
    const float* __restrict__ bl,
    unsigned short* __restrict__ outl, unsigned short* __restrict__ outr)
{
  constexpr int KP = K + 8;                 // padded row length (bf16 units)
  const int row0 = bx * 64;
  if (XBF16) {
    const uint4* X = (const uint4*)X_;      // row = K bf16 = K/8 uint4
    const int CH = K / 8;
    for (int i = threadIdx.x; i < 64 * CH; i += 256) {
      int r = i / CH, c = i % CH;
      int row = row0 + r;
      uint4 v = (row < N_NODES) ? X[(size_t)row * CH + c] : make_uint4(0, 0, 0, 0);
      *(uint4*)&xs[r * KP + c * 8] = v;
    }
  } else {
    const float4* X = (const float4*)X_;
    const int CH = K / 4;
    for (int i = threadIdx.x; i < 64 * CH; i += 256) {
      int r = i / CH, c = i % CH;
      int row = row0 + r;
      float4 v = (row < N_NODES) ? X[(size_t)row * CH + c]
                                 : make_float4(0.f, 0.f, 0.f, 0.f);
      unsigned int lo = (unsigned int)f2bf(v.x) | ((unsigned int)f2bf(v.y) << 16);
      unsigned int hi = (unsigned int)f2bf(v.z) | ((unsigned int)f2bf(v.w) << 16);
      *(uint2*)&xs[r * KP + c * 4] = make_uint2(lo, hi);
    }
  }
  __syncthreads();

  const int lane = threadIdx.x & 63;
  const int w    = threadIdx.x >> 6;
  const int quad = lane >> 4;
  const int l15  = lane & 15;
  const int rloc = w * 16 + l15;            // A-frag row

  floatx4 accl[4], accr[4];
#pragma unroll
  for (int c = 0; c < 4; ++c) { accl[c] = (floatx4)0.f; accr[c] = (floatx4)0.f; }

  const uint4* wbase = (const uint4*)Wb;
#pragma unroll
  for (int ks = 0; ks < K / 32; ++ks) {
    short8 af = *(const short8*)&xs[rloc * KP + ks * 32 + quad * 8];
#pragma unroll
    for (int c = 0; c < 4; ++c) {
      uint4 rl = wbase[((ks * 4 + c) * 2 + 0) * 64 + lane];
      uint4 rr = wbase[((ks * 4 + c) * 2 + 1) * 64 + lane];
      short8 bfl, bfr;
      __builtin_memcpy(&bfl, &rl, 16);
      __builtin_memcpy(&bfr, &rr, 16);
      accl[c] = __builtin_amdgcn_mfma_f32_16x16x32_bf16(af, bfl, accl[c], 0, 0, 0);
      accr[c] = __builtin_amdgcn_mfma_f32_16x16x32_bf16(af, bfr, accr[c], 0, 0, 0);
    }
  }
#pragma unroll
  for (int c = 0; c < 4; ++c) {
    int col = c * 16 + l15;
    float bias = bl[col];
#pragma unroll
    for (int reg = 0; reg < 4; ++reg) {
      int row = row0 + w * 16 + quad * 4 + reg;
      if (row < N_NODES) {
        outl[(size_t)row * H_DIM + col] = f2bf(accl[c][reg] + bias);
        outr[(size_t)row * H_DIM + col] = f2bf(accr[c][reg]);
      }
    }
  }
}

// binA: LDS-binned bucket scatter into fixed-stride bucket regions
// (ebuf[b*MAXB + cursor]); one global atomic per (block,bucket).
// bcur zeroed by pack_all_k (previous dispatch). ei read exactly once.
__global__ __launch_bounds__(256) void binA_k(const int* __restrict__ ei,
                                              int* __restrict__ bcur,
                                              unsigned int* __restrict__ ebuf)
{
  __shared__ int lcnt[256];
  __shared__ int lofs[256];
  __shared__ int lstart[256];
  __shared__ int gstart[256];
  __shared__ int lcur[256];
  __shared__ unsigned int ldata[TILE_A];   // 16 KB
  const int t = threadIdx.x;
  const int e0 = blockIdx.x * TILE_A;
  lcnt[t] = 0;
  __syncthreads();
  int ss[EPT], ds[EPT];
#pragma unroll
  for (int j = 0; j < EPT; ++j) {
    int e = e0 + t + j * 256;              // coalesced
    if (e < N_EDGES) {
      ss[j] = ei[e];
      ds[j] = ei[N_EDGES + e];
      atomicAdd(&lcnt[ds[j] >> 8], 1);
    } else {
      ds[j] = -1;
    }
  }
  __syncthreads();
  int v = lcnt[t];
  lofs[t] = v;
  __syncthreads();
  for (int off = 1; off < 256; off <<= 1) {
    int u = (t >= off) ? lofs[t - off] : 0;
    __syncthreads();
    lofs[t] += u;
    __syncthreads();
  }
  lstart[t] = lofs[t] - v;
  lcur[t]   = lofs[t] - v;
  if (t < NB_SCAN && v > 0) gstart[t] = atomicAdd(&bcur[t], v);
  __syncthreads();
#pragma unroll
  for (int j = 0; j < EPT; ++j) {
    if (ds[j] >= 0) {
      int p = atomicAdd(&lcur[ds[j] >> 8], 1);
      ldata[p] = ((unsigned int)ss[j] << 8) | (unsigned int)(ds[j] & 255);
    }
  }
  __syncthreads();
  int w = t >> 6, lane = t & 63;
  for (int b = w; b < NB_SCAN; b += 4) {
    int st = lstart[b], len = lcnt[b];
    if (len == 0) continue;
    int g = gstart[b];
    unsigned int* dst = ebuf + (size_t)b * MAXB;
    for (int j = lane; j < len; j += 64) {
      int gp = g + j;
      if (gp < MAXB) dst[gp] = ldata[st + j];   // clamp: statistically unreachable
    }
  }
}

// binB body: fused bucket-offset scan (over bcur) + per-bucket counting sort +
// CSR finalize: writes esrc (coalesced) and rowptr.  (edst stays dead: decode
// recovers dst via rowptr binary search.)
__device__ __forceinline__ void binB_body(
    int b, unsigned char* smem,
    const unsigned int* __restrict__ ebuf, const int* __restrict__ bcur,
    int* __restrict__ esrc, int* __restrict__ rowptr)
{
  int* sc    = (int*)smem;                 // 256
  int* ncnt  = sc + 256;                   // 256
  int* nscan = ncnt + 256;                 // 256
  int* ncur  = nscan + 256;                // 256
  int* sh_se = ncur + 256;                 // 2
  unsigned int* sdata = (unsigned int*)(sh_se + 2);   // MAXB
  const int t = threadIdx.x;
  // Bucket offsets: inclusive scan over clamped bucket lengths (196 ints).
  int bl = (t < NB_SCAN) ? min(bcur[t], MAXB) : 0;
  sc[t] = bl;
  __syncthreads();
  for (int off = 1; off < 256; off <<= 1) {
    int u = (t >= off) ? sc[t - off] : 0;
    __syncthreads();
    sc[t] += u;
    __syncthreads();
  }
  if (t == b) { sh_se[0] = sc[t] - bl; sh_se[1] = bl; }
  __syncthreads();
  const int start = sh_se[0], len = sh_se[1];
  const unsigned int* eb = ebuf + (size_t)b * MAXB;
  // Per-node histogram within the bucket.
  ncnt[t] = 0;
  __syncthreads();
  for (int i = t; i < len; i += 256) atomicAdd(&ncnt[eb[i] & 255], 1);
  __syncthreads();
  int v = ncnt[t];
  nscan[t] = v;
  __syncthreads();
  for (int off = 1; off < 256; off <<= 1) {
    int u = (t >= off) ? nscan[t - off] : 0;
    __syncthreads();
    nscan[t] += u;
    __syncthreads();
  }
  ncur[t] = nscan[t] - v;
  __syncthreads();
  for (int i = t; i < len; i += 256) {
    unsigned int e = eb[i];
    int p = atomicAdd(&ncur[e & 255], 1);
    sdata[p] = e >> 8;
  }
  __syncthreads();
  for (int i = t; i < len; i += 256) esrc[start + i] = (int)sdata[i];
  // rowptr: node (b*256+t) owns [start+nscan[t]-v, start+nscan[t])
  int node = b * 256 + t;
  int s0 = start + nscan[t] - v;
  if (node < N_NODES) {
    rowptr[node] = s0;
    if (node == N_NODES - 1) rowptr[N_NODES] = s0 + v;   // == E
  }
}

// Fused independent dispatches: blocks [0,GT1) run gemm1 (depends on pack),
// blocks [GT1,GT1+196) run binB (depends on binA).  No shared data; one LDS
// buffer overlaid (gemm path 33.8 KB dominates -> 4 blocks/CU either way).
__global__ __launch_bounds__(256, 4) void binB_gemm1_k(
    const float* __restrict__ x, const unsigned short* __restrict__ Wb1,
    const float* __restrict__ b1l,
    unsigned short* __restrict__ m1, unsigned short* __restrict__ xr,
    const unsigned int* __restrict__ ebuf, const int* __restrict__ bcur,
    int* __restrict__ esrc, int* __restrict__ rowptr)
{
  __shared__ __align__(16) unsigned char smem[64 * (F_IN + 8) * 2];  // 33792 B
  if (blockIdx.x < GT1) {
    gemm_body<F_IN, false>(blockIdx.x, (unsigned short*)smem, x, Wb1, b1l, m1, xr);
  } else {
    binB_body(blockIdx.x - GT1, smem, ebuf, bcur, esrc, rowptr);
  }
}

// Layer-2 GEMM stays standalone (depends on agg1).
__global__ __launch_bounds__(256, 4) void gemm2_k(
    const void* __restrict__ X_, const unsigned short* __restrict__ Wb,
    const float* __restrict__ bl,
    unsigned short* __restrict__ outl, unsigned short* __restrict__ outr)
{
  __shared__ __align__(16) unsigned short xs[64 * (H_DIM + 8)];
  gemm_body<H_DIM, true>(blockIdx.x, xs, X_, Wb, bl, outl, outr);
}

// ---- Fused aggregation: wave per dst node, lane = feature, bf16 everywhere ----
__device__ __forceinline__ float agg_row_b(const int* __restrict__ esrc,
                                           const unsigned short* __restrict__ m,
                                           int b, int e, int lane)
{
  float a0 = 0.f, a1 = 0.f, a2 = 0.f, a3 = 0.f;
  float a4 = 0.f, a5 = 0.f, a6 = 0.f, a7 = 0.f;
  int i = b;
  for (; i + 8 <= e; i += 8) {
    int s0 = esrc[i],     s1 = esrc[i + 1], s2 = esrc[i + 2], s3 = esrc[i + 3];
    int s4 = esrc[i + 4], s5 = esrc[i + 5], s6 = esrc[i + 6], s7 = esrc[i + 7];
    a0 += bf2f(m[(size_t)s0 * H_DIM + lane]);
    a1 += bf2f(m[(size_t)s1 * H_DIM + lane]);
    a2 += bf2f(m[(size_t)s2 * H_DIM + lane]);
    a3 += bf2f(m[(size_t)s3 * H_DIM + lane]);
    a4 += bf2f(m[(size_t)s4 * H_DIM + lane]);
    a5 += bf2f(m[(size_t)s5 * H_DIM + lane]);
    a6 += bf2f(m[(size_t)s6 * H_DIM + lane]);
    a7 += bf2f(m[(size_t)s7 * H_DIM + lane]);
  }
  for (; i + 4 <= e; i += 4) {
    int s0 = esrc[i], s1 = esrc[i + 1], s2 = esrc[i + 2], s3 = esrc[i + 3];
    a0 += bf2f(m[(size_t)s0 * H_DIM + lane]);
    a1 += bf2f(m[(size_t)s1 * H_DIM + lane]);
    a2 += bf2f(m[(size_t)s2 * H_DIM + lane]);
    a3 += bf2f(m[(size_t)s3 * H_DIM + lane]);
  }
  for (; i < e; ++i) a0 += bf2f(m[(size_t)esrc[i] * H_DIM + lane]);
  return ((a0 + a1) + (a2 + a3)) + ((a4 + a5) + (a6 + a7));
}

// h = relu(mean m1 + xr) -> bf16
__global__ __launch_bounds__(256) void agg1_k(
    const int* __restrict__ rowptr, const int* __restrict__ esrc,
    const unsigned short* __restrict__ m, const unsigned short* __restrict__ xr,
    unsigned short* __restrict__ h)
{
  int gid = blockIdx.x * 256 + threadIdx.x;
  int row = gid >> 6, lane = gid & 63;
  if (row >= N_NODES) return;
  int b = rowptr[row], e = rowptr[row + 1];
  float acc = agg_row_b(esrc, m, b, e, lane);
  float dv = fmaxf((float)(e - b), 1.f);
  size_t o = (size_t)row * H_DIM + lane;
  h[o] = f2bf(fmaxf(acc / dv + bf2f(xr[o]), 0.f));
}

// z = unitnorm(mean m2 + hr) -> fp32 d_out + bf16 copy (decode gathers)
__global__ __launch_bounds__(256) void agg2_k(
    const int* __restrict__ rowptr, const int* __restrict__ esrc,
    const unsigned short* __restrict__ m, const unsigned short* __restrict__ hr,
    float* __restrict__ zout, unsigned short* __restrict__ zb)
{
  int gid = blockIdx.x * 256 + threadIdx.x;
  int row = gid >> 6, lane = gid & 63;
  if (row >= N_NODES) return;
  int b = rowptr[row], e = rowptr[row + 1];
  float acc = agg_row_b(esrc, m, b, e, lane);
  float dv = fmaxf((float)(e - b), 1.f);
  size_t o = (size_t)row * H_DIM + lane;
  float v = acc / dv + bf2f(hr[o]);
  float ss = v * v;
#pragma unroll
  for (int mm = 32; mm >= 1; mm >>= 1) ss += __shfl_xor(ss, mm, 64);
  float z = v * rsqrtf(fmaxf(ss, 1e-30f));
  zout[o] = z;
  zb[o] = f2bf(z);
}

// Decode: thread-per-edge, block = 64-node dst window.  The 64 dst z-rows
// (8 KB) are staged once in LDS (XOR-swizzled: 128B row stride is a 16-way
// bank conflict otherwise); each edge's dst index is recovered by binary
// search over the rowptr window (65 ints in LDS) -- edst never materialized.
// Src rows are per-thread uint4 gathers (L1/L2-cached); dot runs in-thread,
// so no per-edge cross-lane ops.  Consecutive lanes share the dst row ->
// LDS broadcast.
__global__ __launch_bounds__(256) void decode_lds_k(
    const int* __restrict__ rowptr, const int* __restrict__ esrc,
    const unsigned short* __restrict__ zb, float* __restrict__ loss_slot)
{
  __shared__ __align__(16) uint4 zrows[SUBN * 8];   // 8 KB, swizzled chunks
  __shared__ int sh_rp[SUBN + 1];
  const int t = threadIdx.x;
  const int node0 = blockIdx.x * SUBN;
  const int nr = min(SUBN, N_NODES - node0);        // 64 (last block: 16)
  // Stage dst rows: row r chunk c stored at [r*8 + (c ^ (r&7))].
  for (int i = t; i < nr * 8; i += 256) {
    int r = i >> 3, c = i & 7;
    uint4 v = ((const uint4*)(zb + (size_t)(node0 + r) * H_DIM))[c];
    zrows[r * 8 + (c ^ (r & 7))] = v;
  }
  if (t <= nr) sh_rp[t] = rowptr[node0 + t];
  __syncthreads();
  const int estart = sh_rp[0], eend = sh_rp[nr];
  float part = 0.f;
  for (int e = estart + t; e < eend; e += 256) {
    // Binary search: largest r in [0,nr) with sh_rp[r] <= e.
    int lo = 0, hi = nr;
    while (hi - lo > 1) {
      int mid = (lo + hi) >> 1;
      if (sh_rp[mid] <= e) lo = mid; else hi = mid;
    }
    const int r = lo;
    const int s = esrc[e];
    const uint4* zs = (const uint4*)(zb + (size_t)s * H_DIM);
    float p = 0.f;
#pragma unroll
    for (int c = 0; c < 8; ++c) {
      uint4 a = zs[c];
      uint4 b = zrows[r * 8 + (c ^ (r & 7))];
      unsigned int au[4] = {a.x, a.y, a.z, a.w};
      unsigned int bu[4] = {b.x, b.y, b.z, b.w};
#pragma unroll
      for (int j = 0; j < 4; ++j) {
        p = fmaf(bflo(au[j]), bflo(bu[j]), p);
        p = fmaf(bfhi(au[j]), bfhi(bu[j]), p);
      }
    }
    part += fmaxf(-p, 0.f) + log1pf(expf(-fabsf(p)));
  }
#pragma unroll
  for (int m = 32; m >= 1; m >>= 1) part += __shfl_xor(part, m, 64);
  __shared__ float sbuf[4];
  int lane = t & 63, w = t >> 6;
  if (lane == 0) sbuf[w] = part;
  __syncthreads();
  if (t == 0)
    atomicAdd(loss_slot, (sbuf[0] + sbuf[1] + sbuf[2] + sbuf[3]) * (1.0f / N_EDGES));
}

extern "C" void kernel_launch(void* const* d_in, const int* in_sizes, int n_in,
                              void* d_out, int out_size, void* d_ws, size_t ws_size,
                              hipStream_t stream)
{
  (void)in_sizes; (void)n_in; (void)out_size; (void)ws_size;
  const float* x   = (const float*)d_in[0];
  const int*   ei  = (const int*)d_in[1];
  const float* W1l = (const float*)d_in[2];
  const float* b1l = (const float*)d_in[3];
  const float* W1r = (const float*)d_in[4];
  const float* W2l = (const float*)d_in[5];
  const float* b2l = (const float*)d_in[6];
  const float* W2r = (const float*)d_in[7];
  float* out = (float*)d_out;  // fp32: z [N*H] ++ loss [1]
  float* loss_slot = out + (size_t)N_NODES * H_DIM;

  const size_t NH = (size_t)N_NODES * H_DIM;
  // uA = m1 then m2; uB = h then zb; uC = xr then hr (all bf16).
  unsigned short* uA = (unsigned short*)d_ws;   // NH ushort
  unsigned short* uB = uA + NH;                 // NH ushort
  unsigned short* uC = uB + NH;                 // NH ushort
  // Wb right after bf16 buffers: 19.2 MB offset is 16B-aligned (uint4 access).
  unsigned short* Wb1 = uC + NH;                             // 64 KB
  unsigned short* Wb2 = Wb1 + (F_IN / 32) * 4 * 2 * 64 * 8;  // 16 KB
  int* rowptr = (int*)(Wb2 + (H_DIM / 32) * 4 * 2 * 64 * 8); // N+1
  int* esrc   = rowptr + N_NODES + 1;   // E
  int* bcur   = esrc + N_EDGES;         // NB_SCAN
  unsigned int* ebuf = (unsigned int*)(bcur + NB_SCAN);      // NB_SCAN*MAXB (4.4 MB)

  dim3 blk(256);
  dim3 g_node((N_NODES * 64 + 255) / 256);
  dim3 g_binA((N_EDGES + TILE_A - 1) / TILE_A);   // 196
  dim3 g_fuse(GT1 + NB_SCAN);                     // 978
  dim3 g_tile(GT1);                               // 782
  dim3 g_dec(DEC_GRID);                           // 782

  // Pack W1+W2 fragments (bf16) + zero loss slot + zero bucket cursors
  pack_all_k<<<dim3(20), blk, 0, stream>>>(W1l, W1r, W2l, W2r, Wb1, Wb2,
                                           loss_slot, bcur);
  // CSR build stage A: LDS-binned bucket scatter
  binA_k<<<g_binA, blk, 0, stream>>>(ei, bcur, ebuf);
  // Fused: gemm1 (m1 -> uA, xr -> uC) || binB (esrc+rowptr) — independent
  binB_gemm1_k<<<g_fuse, blk, 0, stream>>>(x, Wb1, b1l, uA, uC,
                                           ebuf, bcur, esrc, rowptr);
  agg1_k<<<g_node, blk, 0, stream>>>(rowptr, esrc, uA, uC, uB);
  // Layer 2 (MFMA, bf16 input): m2 -> uA, hr -> uC (bf16)
  gemm2_k<<<g_tile, blk, 0, stream>>>(uB, Wb2, b2l, uA, uC);
  agg2_k<<<g_node, blk, 0, stream>>>(rowptr, esrc, uA, uC, out, uB);
  // Decode + loss (thread-per-edge, LDS dst window, rowptr binary search)
  decode_lds_k<<<g_dec, blk, 0, stream>>>(rowptr, esrc, uB, loss_slot);
}

// Round 4
// 236.711 us; speedup vs baseline: 1.7487x; 1.0120x over previous
//
#include <hip/hip_runtime.h>

// Problem constants (SVGA_7318624272625)
#define N_NODES 50000
#define N_EDGES 800000
#define F_IN    256
#define H_DIM   64
#define NB_SCAN ((N_NODES + 255) / 256)   // 196 dst buckets (256 nodes each)
#define TILE_A  4096                       // edges per binA block -> 196 blocks
#define EPT     (TILE_A / 256)             // edges per thread in binA (16)
#define MAXB    5632                       // max edges per bucket (avg 4081, +24 sigma)
#define GT1     ((N_NODES + 63) / 64)      // gemm1 tile blocks (782)
#define SUBN    64                         // decode: dst nodes per block
#define DEC_GRID ((N_NODES + SUBN - 1) / SUBN)   // 782

typedef __attribute__((ext_vector_type(8))) short short8;
typedef __attribute__((ext_vector_type(4))) float floatx4;

__device__ __forceinline__ unsigned short f2bf(float f) {  // RNE fp32->bf16
  unsigned int u;
  __builtin_memcpy(&u, &f, 4);
  u += 0x7fffu + ((u >> 16) & 1u);
  return (unsigned short)(u >> 16);
}
__device__ __forceinline__ float bf2f(unsigned short s) {
  unsigned int v = ((unsigned int)s) << 16; float f; __builtin_memcpy(&f, &v, 4); return f;
}
__device__ __forceinline__ float bflo(unsigned int u) {
  unsigned int v = u << 16; float f; __builtin_memcpy(&f, &v, 4); return f;
}
__device__ __forceinline__ float bfhi(unsigned int u) {
  unsigned int v = u & 0xffff0000u; float f; __builtin_memcpy(&f, &v, 4); return f;
}

// Pack helper: W[K,64] (fp32) -> bf16 MFMA B-fragments, frag id
// f = (ks*4+c)*2+m ; lane L, j holds B[k=ks*32+(L>>4)*8+j][n=c*16+(L&15)].
template<int K>
__device__ __forceinline__ void pack_body(int t, const float* __restrict__ Wl,
                                          const float* __restrict__ Wr,
                                          unsigned short* __restrict__ Wb)
{
  int lane = t & 63;
  int f    = t >> 6;
  int m    = f & 1;
  int c    = (f >> 1) & 3;
  int ks   = f >> 3;
  const float* W = m ? Wr : Wl;
  int quad = lane >> 4, l15 = lane & 15;
  int col = c * 16 + l15;
  unsigned short u[8];
#pragma unroll
  for (int j = 0; j < 8; ++j) {
    int k = ks * 32 + quad * 8 + j;
    u[j] = f2bf(W[k * H_DIM + col]);
  }
  uint4 v;
  __builtin_memcpy(&v, u, 16);
  ((uint4*)Wb)[t] = v;
}

// Fused pack: blocks 0-15 pack W1 (4096 frags*lanes), 16-19 pack W2 (1024);
// block 0 also zeroes the loss slot and the bucket cursors (binA runs in a
// LATER dispatch on the same stream, so this ordering is safe).
__global__ __launch_bounds__(256) void pack_all_k(
    const float* __restrict__ W1l, const float* __restrict__ W1r,
    const float* __restrict__ W2l, const float* __restrict__ W2r,
    unsigned short* __restrict__ Wb1, unsigned short* __restrict__ Wb2,
    float* __restrict__ loss_slot, int* __restrict__ bcur)
{
  if (blockIdx.x == 0) {
    if (threadIdx.x == 0) loss_slot[0] = 0.f;
    if (threadIdx.x < NB_SCAN) bcur[threadIdx.x] = 0;
  }
  int b = blockIdx.x;
  if (b < 16) {
    pack_body<F_IN>(b * 256 + threadIdx.x, W1l, W1r, Wb1);
  } else {
    pack_body<H_DIM>((b - 16) * 256 + threadIdx.x, W2l, W2r, Wb2);
  }
}

// MFMA dual-GEMM body: outl = bf16(X@Wl + bl), outr = bf16(X@Wr).
// xs must point at >= 64*(K+8) ushorts of LDS (16B aligned).
template<int K, bool XBF16>
__device__ __forceinline__ void gemm_body(
    int bx, unsigned short* xs,
    const void* __restrict__ X_,
    const unsigned short* __restrict__ Wb,
    const float* __restrict__ bl,
    unsigned short* __restrict__ outl, unsigned short* __restrict__ outr)
{
  constexpr int KP = K + 8;                 // padded row length (bf16 units)
  const int row0 = bx * 64;
  if (XBF16) {
    const uint4* X = (const uint4*)X_;      // row = K bf16 = K/8 uint4
    const int CH = K / 8;
    for (int i = threadIdx.x; i < 64 * CH; i += 256) {
      int r = i / CH, c = i % CH;
      int row = row0 + r;
      uint4 v = (row < N_NODES) ? X[(size_t)row * CH + c] : make_uint4(0, 0, 0, 0);
      *(uint4*)&xs[r * KP + c * 8] = v;
    }
  } else {
    const float4* X = (const float4*)X_;
    const int CH = K / 4;
    for (int i = threadIdx.x; i < 64 * CH; i += 256) {
      int r = i / CH, c = i % CH;
      int row = row0 + r;
      float4 v = (row < N_NODES) ? X[(size_t)row * CH + c]
                                 : make_float4(0.f, 0.f, 0.f, 0.f);
      unsigned int lo = (unsigned int)f2bf(v.x) | ((unsigned int)f2bf(v.y) << 16);
      unsigned int hi = (unsigned int)f2bf(v.z) | ((unsigned int)f2bf(v.w) << 16);
      *(uint2*)&xs[r * KP + c * 4] = make_uint2(lo, hi);
    }
  }
  __syncthreads();

  const int lane = threadIdx.x & 63;
  const int w    = threadIdx.x >> 6;
  const int quad = lane >> 4;
  const int l15  = lane & 15;
  const int rloc = w * 16 + l15;            // A-frag row

  floatx4 accl[4], accr[4];
#pragma unroll
  for (int c = 0; c < 4; ++c) { accl[c] = (floatx4)0.f; accr[c] = (floatx4)0.f; }

  const uint4* wbase = (const uint4*)Wb;
#pragma unroll
  for (int ks = 0; ks < K / 32; ++ks) {
    short8 af = *(const short8*)&xs[rloc * KP + ks * 32 + quad * 8];
#pragma unroll
    for (int c = 0; c < 4; ++c) {
      uint4 rl = wbase[((ks * 4 + c) * 2 + 0) * 64 + lane];
      uint4 rr = wbase[((ks * 4 + c) * 2 + 1) * 64 + lane];
      short8 bfl, bfr;
      __builtin_memcpy(&bfl, &rl, 16);
      __builtin_memcpy(&bfr, &rr, 16);
      accl[c] = __builtin_amdgcn_mfma_f32_16x16x32_bf16(af, bfl, accl[c], 0, 0, 0);
      accr[c] = __builtin_amdgcn_mfma_f32_16x16x32_bf16(af, bfr, accr[c], 0, 0, 0);
    }
  }
#pragma unroll
  for (int c = 0; c < 4; ++c) {
    int col = c * 16 + l15;
    float bias = bl[col];
#pragma unroll
    for (int reg = 0; reg < 4; ++reg) {
      int row = row0 + w * 16 + quad * 4 + reg;
      if (row < N_NODES) {
        outl[(size_t)row * H_DIM + col] = f2bf(accl[c][reg] + bias);
        outr[(size_t)row * H_DIM + col] = f2bf(accr[c][reg]);
      }
    }
  }
}

// binA: LDS-binned bucket scatter into fixed-stride bucket regions
// (ebuf[b*MAXB + cursor]); one global atomic per (block,bucket).
// bcur zeroed by pack_all_k (previous dispatch). ei read exactly once.
__global__ __launch_bounds__(256) void binA_k(const int* __restrict__ ei,
                                              int* __restrict__ bcur,
                                              unsigned int* __restrict__ ebuf)
{
  __shared__ int lcnt[256];
  __shared__ int lofs[256];
  __shared__ int lstart[256];
  __shared__ int gstart[256];
  __shared__ int lcur[256];
  __shared__ unsigned int ldata[TILE_A];   // 16 KB
  const int t = threadIdx.x;
  const int e0 = blockIdx.x * TILE_A;
  lcnt[t] = 0;
  __syncthreads();
  int ss[EPT], ds[EPT];
#pragma unroll
  for (int j = 0; j < EPT; ++j) {
    int e = e0 + t + j * 256;              // coalesced
    if (e < N_EDGES) {
      ss[j] = ei[e];
      ds[j] = ei[N_EDGES + e];
      atomicAdd(&lcnt[ds[j] >> 8], 1);
    } else {
      ds[j] = -1;
    }
  }
  __syncthreads();
  int v = lcnt[t];
  lofs[t] = v;
  __syncthreads();
  for (int off = 1; off < 256; off <<= 1) {
    int u = (t >= off) ? lofs[t - off] : 0;
    __syncthreads();
    lofs[t] += u;
    __syncthreads();
  }
  lstart[t] = lofs[t] - v;
  lcur[t]   = lofs[t] - v;
  if (t < NB_SCAN && v > 0) gstart[t] = atomicAdd(&bcur[t], v);
  __syncthreads();
#pragma unroll
  for (int j = 0; j < EPT; ++j) {
    if (ds[j] >= 0) {
      int p = atomicAdd(&lcur[ds[j] >> 8], 1);
      ldata[p] = ((unsigned int)ss[j] << 8) | (unsigned int)(ds[j] & 255);
    }
  }
  __syncthreads();
  int w = t >> 6, lane = t & 63;
  for (int b = w; b < NB_SCAN; b += 4) {
    int st = lstart[b], len = lcnt[b];
    if (len == 0) continue;
    int g = gstart[b];
    unsigned int* dst = ebuf + (size_t)b * MAXB;
    for (int j = lane; j < len; j += 64) {
      int gp = g + j;
      if (gp < MAXB) dst[gp] = ldata[st + j];   // clamp: statistically unreachable
    }
  }
}

// binB body: fused bucket-offset scan (over bcur) + per-bucket counting sort +
// CSR finalize: writes esrc (coalesced) and rowptr.  (edst stays dead: decode
// recovers dst via rowptr binary search.)
__device__ __forceinline__ void binB_body(
    int b, unsigned char* smem,
    const unsigned int* __restrict__ ebuf, const int* __restrict__ bcur,
    int* __restrict__ esrc, int* __restrict__ rowptr)
{
  int* sc    = (int*)smem;                 // 256
  int* ncnt  = sc + 256;                   // 256
  int* nscan = ncnt + 256;                 // 256
  int* ncur  = nscan + 256;                // 256
  int* sh_se = ncur + 256;                 // 2
  unsigned int* sdata = (unsigned int*)(sh_se + 2);   // MAXB
  const int t = threadIdx.x;
  // Bucket offsets: inclusive scan over clamped bucket lengths (196 ints).
  int bl = (t < NB_SCAN) ? min(bcur[t], MAXB) : 0;
  sc[t] = bl;
  __syncthreads();
  for (int off = 1; off < 256; off <<= 1) {
    int u = (t >= off) ? sc[t - off] : 0;
    __syncthreads();
    sc[t] += u;
    __syncthreads();
  }
  if (t == b) { sh_se[0] = sc[t] - bl; sh_se[1] = bl; }
  __syncthreads();
  const int start = sh_se[0], len = sh_se[1];
  const unsigned int* eb = ebuf + (size_t)b * MAXB;
  // Per-node histogram within the bucket.
  ncnt[t] = 0;
  __syncthreads();
  for (int i = t; i < len; i += 256) atomicAdd(&ncnt[eb[i] & 255], 1);
  __syncthreads();
  int v = ncnt[t];
  nscan[t] = v;
  __syncthreads();
  for (int off = 1; off < 256; off <<= 1) {
    int u = (t >= off) ? nscan[t - off] : 0;
    __syncthreads();
    nscan[t] += u;
    __syncthreads();
  }
  ncur[t] = nscan[t] - v;
  __syncthreads();
  for (int i = t; i < len; i += 256) {
    unsigned int e = eb[i];
    int p = atomicAdd(&ncur[e & 255], 1);
    sdata[p] = e >> 8;
  }
  __syncthreads();
  for (int i = t; i < len; i += 256) esrc[start + i] = (int)sdata[i];
  // rowptr: node (b*256+t) owns [start+nscan[t]-v, start+nscan[t])
  int node = b * 256 + t;
  int s0 = start + nscan[t] - v;
  if (node < N_NODES) {
    rowptr[node] = s0;
    if (node == N_NODES - 1) rowptr[N_NODES] = s0 + v;   // == E
  }
}

// Fused independent dispatches: blocks [0,GT1) run gemm1 (depends on pack),
// blocks [GT1,GT1+196) run binB (depends on binA).  No shared data; one LDS
// buffer overlaid (gemm path 33.8 KB dominates -> 4 blocks/CU either way).
__global__ __launch_bounds__(256, 4) void binB_gemm1_k(
    const float* __restrict__ x, const unsigned short* __restrict__ Wb1,
    const float* __restrict__ b1l,
    unsigned short* __restrict__ m1, unsigned short* __restrict__ xr,
    const unsigned int* __restrict__ ebuf, const int* __restrict__ bcur,
    int* __restrict__ esrc, int* __restrict__ rowptr)
{
  __shared__ __align__(16) unsigned char smem[64 * (F_IN + 8) * 2];  // 33792 B
  if (blockIdx.x < GT1) {
    gemm_body<F_IN, false>(blockIdx.x, (unsigned short*)smem, x, Wb1, b1l, m1, xr);
  } else {
    binB_body(blockIdx.x - GT1, smem, ebuf, bcur, esrc, rowptr);
  }
}

// Layer-2 GEMM stays standalone (depends on agg1).
__global__ __launch_bounds__(256, 4) void gemm2_k(
    const void* __restrict__ X_, const unsigned short* __restrict__ Wb,
    const float* __restrict__ bl,
    unsigned short* __restrict__ outl, unsigned short* __restrict__ outr)
{
  __shared__ __align__(16) unsigned short xs[64 * (H_DIM + 8)];
  gemm_body<H_DIM, true>(blockIdx.x, xs, X_, Wb, bl, outl, outr);
}

// ---- Quarter-wave aggregation ----
// Wave per dst node; 16 lanes per edge (lane l15 holds features l15*4..+3 as
// uint2), 4 edges in flight per wave load instr, 2-deep unroll -> 8 edges in
// flight.  4x fewer VMEM instructions than lane-per-feature at same bytes.
// Quarter g handles edges i = b+g, b+g+4, ...; end combine via shfl_xor 16,32.
__device__ __forceinline__ void agg_quad(const int* __restrict__ esrc,
                                         const unsigned short* __restrict__ m,
                                         int b, int e, int g, int l15,
                                         float* __restrict__ a)
{
  float a0 = 0.f, a1 = 0.f, a2 = 0.f, a3 = 0.f;
  float b0 = 0.f, b1 = 0.f, b2 = 0.f, b3 = 0.f;
  int i = b + g;
  for (; i + 4 < e; i += 8) {
    int s0 = esrc[i], s1 = esrc[i + 4];
    uint2 v0 = *(const uint2*)(m + (size_t)s0 * H_DIM + l15 * 4);
    uint2 v1 = *(const uint2*)(m + (size_t)s1 * H_DIM + l15 * 4);
    a0 += bflo(v0.x); a1 += bfhi(v0.x); a2 += bflo(v0.y); a3 += bfhi(v0.y);
    b0 += bflo(v1.x); b1 += bfhi(v1.x); b2 += bflo(v1.y); b3 += bfhi(v1.y);
  }
  if (i < e) {
    int s0 = esrc[i];
    uint2 v0 = *(const uint2*)(m + (size_t)s0 * H_DIM + l15 * 4);
    a0 += bflo(v0.x); a1 += bfhi(v0.x); a2 += bflo(v0.y); a3 += bfhi(v0.y);
  }
  a[0] = a0 + b0; a[1] = a1 + b1; a[2] = a2 + b2; a[3] = a3 + b3;
  // Combine the 4 quarters: lanes differ in bits 4,5.
#pragma unroll
  for (int j = 0; j < 4; ++j) {
    a[j] += __shfl_xor(a[j], 16, 64);
    a[j] += __shfl_xor(a[j], 32, 64);
  }
}

// h = relu(mean m1 + xr) -> bf16
__global__ __launch_bounds__(256) void agg1_k(
    const int* __restrict__ rowptr, const int* __restrict__ esrc,
    const unsigned short* __restrict__ m, const unsigned short* __restrict__ xr,
    unsigned short* __restrict__ h)
{
  int gid = blockIdx.x * 256 + threadIdx.x;
  int row = gid >> 6;
  if (row >= N_NODES) return;
  int lane = threadIdx.x & 63, g = lane >> 4, l15 = lane & 15;
  int b = rowptr[row], e = rowptr[row + 1];
  float a[4];
  agg_quad(esrc, m, b, e, g, l15, a);
  if (g == 0) {
    float dv = fmaxf((float)(e - b), 1.f);
    float inv = 1.f / dv;
    uint2 rx = *(const uint2*)(xr + (size_t)row * H_DIM + l15 * 4);
    float h0 = fmaxf(a[0] * inv + bflo(rx.x), 0.f);
    float h1 = fmaxf(a[1] * inv + bfhi(rx.x), 0.f);
    float h2 = fmaxf(a[2] * inv + bflo(rx.y), 0.f);
    float h3 = fmaxf(a[3] * inv + bfhi(rx.y), 0.f);
    uint2 o;
    o.x = (unsigned int)f2bf(h0) | ((unsigned int)f2bf(h1) << 16);
    o.y = (unsigned int)f2bf(h2) | ((unsigned int)f2bf(h3) << 16);
    *(uint2*)(h + (size_t)row * H_DIM + l15 * 4) = o;
  }
}

// z = unitnorm(mean m2 + hr) -> fp32 d_out + bf16 copy (decode gathers)
__global__ __launch_bounds__(256) void agg2_k(
    const int* __restrict__ rowptr, const int* __restrict__ esrc,
    const unsigned short* __restrict__ m, const unsigned short* __restrict__ hr,
    float* __restrict__ zout, unsigned short* __restrict__ zb)
{
  int gid = blockIdx.x * 256 + threadIdx.x;
  int row = gid >> 6;
  if (row >= N_NODES) return;
  int lane = threadIdx.x & 63, g = lane >> 4, l15 = lane & 15;
  int b = rowptr[row], e = rowptr[row + 1];
  float a[4];
  agg_quad(esrc, m, b, e, g, l15, a);
  float dv = fmaxf((float)(e - b), 1.f);
  float inv = 1.f / dv;
  uint2 rx = *(const uint2*)(hr + (size_t)row * H_DIM + l15 * 4);
  float v0 = a[0] * inv + bflo(rx.x);
  float v1 = a[1] * inv + bfhi(rx.x);
  float v2 = a[2] * inv + bflo(rx.y);
  float v3 = a[3] * inv + bfhi(rx.y);
  float ss = v0 * v0 + v1 * v1 + v2 * v2 + v3 * v3;
  // All quarters hold identical values; reduce across the 16-lane feature dim.
#pragma unroll
  for (int mm = 8; mm >= 1; mm >>= 1) ss += __shfl_xor(ss, mm, 64);
  float rs = rsqrtf(fmaxf(ss, 1e-30f));
  if (g == 0) {
    float z0 = v0 * rs, z1 = v1 * rs, z2 = v2 * rs, z3 = v3 * rs;
    *(float4*)(zout + (size_t)row * H_DIM + l15 * 4) = make_float4(z0, z1, z2, z3);
    uint2 o;
    o.x = (unsigned int)f2bf(z0) | ((unsigned int)f2bf(z1) << 16);
    o.y = (unsigned int)f2bf(z2) | ((unsigned int)f2bf(z3) << 16);
    *(uint2*)(zb + (size_t)row * H_DIM + l15 * 4) = o;
  }
}

// Decode: thread-per-edge, block = 64-node dst window.  The 64 dst z-rows
// (8 KB) are staged once in LDS (XOR-swizzled vs the 128B-stride conflict);
// dst index recovered by binary search over the rowptr window (edst dead).
// 2 edges per thread per iteration for 2x memory-level parallelism.
__global__ __launch_bounds__(256) void decode_lds_k(
    const int* __restrict__ rowptr, const int* __restrict__ esrc,
    const unsigned short* __restrict__ zb, float* __restrict__ loss_slot)
{
  __shared__ __align__(16) uint4 zrows[SUBN * 8];   // 8 KB, swizzled chunks
  __shared__ int sh_rp[SUBN + 1];
  const int t = threadIdx.x;
  const int node0 = blockIdx.x * SUBN;
  const int nr = min(SUBN, N_NODES - node0);        // 64 (last block: 16)
  // Stage dst rows: row r chunk c stored at [r*8 + (c ^ (r&7))].
  for (int i = t; i < nr * 8; i += 256) {
    int r = i >> 3, c = i & 7;
    uint4 v = ((const uint4*)(zb + (size_t)(node0 + r) * H_DIM))[c];
    zrows[r * 8 + (c ^ (r & 7))] = v;
  }
  if (t <= nr) sh_rp[t] = rowptr[node0 + t];
  __syncthreads();
  const int estart = sh_rp[0], eend = sh_rp[nr];
  float part = 0.f;
  for (int e = estart + t; e < eend; e += 512) {
    int e2 = e + 256;
    bool has2 = (e2 < eend);
    // Binary search both edges (trip count uniform: log2(nr)).
    int lo = 0, hi = nr;
    while (hi - lo > 1) {
      int mid = (lo + hi) >> 1;
      if (sh_rp[mid] <= e) lo = mid; else hi = mid;
    }
    const int r1 = lo;
    hi = nr;                                 // e2 > e -> search from r1
    while (hi - lo > 1) {
      int mid = (lo + hi) >> 1;
      if (sh_rp[mid] <= e2) lo = mid; else hi = mid;
    }
    const int r2 = lo;
    const int s1 = esrc[e];
    const int s2 = has2 ? esrc[e2] : s1;
    const uint4* zs1 = (const uint4*)(zb + (size_t)s1 * H_DIM);
    const uint4* zs2 = (const uint4*)(zb + (size_t)s2 * H_DIM);
    float p1 = 0.f, p2 = 0.f;
#pragma unroll
    for (int c = 0; c < 8; ++c) {
      uint4 a1 = zs1[c], b1 = zrows[r1 * 8 + (c ^ (r1 & 7))];
      uint4 a2 = zs2[c], b2 = zrows[r2 * 8 + (c ^ (r2 & 7))];
      unsigned int au1[4] = {a1.x, a1.y, a1.z, a1.w};
      unsigned int bu1[4] = {b1.x, b1.y, b1.z, b1.w};
      unsigned int au2[4] = {a2.x, a2.y, a2.z, a2.w};
      unsigned int bu2[4] = {b2.x, b2.y, b2.z, b2.w};
#pragma unroll
      for (int j = 0; j < 4; ++j) {
        p1 = fmaf(bflo(au1[j]), bflo(bu1[j]), p1);
        p1 = fmaf(bfhi(au1[j]), bfhi(bu1[j]), p1);
        p2 = fmaf(bflo(au2[j]), bflo(bu2[j]), p2);
        p2 = fmaf(bfhi(au2[j]), bfhi(bu2[j]), p2);
      }
    }
    part += fmaxf(-p1, 0.f) + log1pf(expf(-fabsf(p1)));
    if (has2) part += fmaxf(-p2, 0.f) + log1pf(expf(-fabsf(p2)));
  }
#pragma unroll
  for (int m = 32; m >= 1; m >>= 1) part += __shfl_xor(part, m, 64);
  __shared__ float sbuf[4];
  int lane = t & 63, w = t >> 6;
  if (lane == 0) sbuf[w] = part;
  __syncthreads();
  if (t == 0)
    atomicAdd(loss_slot, (sbuf[0] + sbuf[1] + sbuf[2] + sbuf[3]) * (1.0f / N_EDGES));
}

extern "C" void kernel_launch(void* const* d_in, const int* in_sizes, int n_in,
                              void* d_out, int out_size, void* d_ws, size_t ws_size,
                              hipStream_t stream)
{
  (void)in_sizes; (void)n_in; (void)out_size; (void)ws_size;
  const float* x   = (const float*)d_in[0];
  const int*   ei  = (const int*)d_in[1];
  const float* W1l = (const float*)d_in[2];
  const float* b1l = (const float*)d_in[3];
  const float* W1r = (const float*)d_in[4];
  const float* W2l = (const float*)d_in[5];
  const float* b2l = (const float*)d_in[6];
  const float* W2r = (const float*)d_in[7];
  float* out = (float*)d_out;  // fp32: z [N*H] ++ loss [1]
  float* loss_slot = out + (size_t)N_NODES * H_DIM;

  const size_t NH = (size_t)N_NODES * H_DIM;
  // uA = m1 then m2; uB = h then zb; uC = xr then hr (all bf16).
  unsigned short* uA = (unsigned short*)d_ws;   // NH ushort
  unsigned short* uB = uA + NH;                 // NH ushort
  unsigned short* uC = uB + NH;                 // NH ushort
  // Wb right after bf16 buffers: 19.2 MB offset is 16B-aligned (uint4 access).
  unsigned short* Wb1 = uC + NH;                             // 64 KB
  unsigned short* Wb2 = Wb1 + (F_IN / 32) * 4 * 2 * 64 * 8;  // 16 KB
  int* rowptr = (int*)(Wb2 + (H_DIM / 32) * 4 * 2 * 64 * 8); // N+1
  int* esrc   = rowptr + N_NODES + 1;   // E
  int* bcur   = esrc + N_EDGES;         // NB_SCAN
  unsigned int* ebuf = (unsigned int*)(bcur + NB_SCAN);      // NB_SCAN*MAXB (4.4 MB)

  dim3 blk(256);
  dim3 g_node((N_NODES * 64 + 255) / 256);
  dim3 g_binA((N_EDGES + TILE_A - 1) / TILE_A);   // 196
  dim3 g_fuse(GT1 + NB_SCAN);                     // 978
  dim3 g_tile(GT1);                               // 782
  dim3 g_dec(DEC_GRID);                           // 782

  // Pack W1+W2 fragments (bf16) + zero loss slot + zero bucket cursors
  pack_all_k<<<dim3(20), blk, 0, stream>>>(W1l, W1r, W2l, W2r, Wb1, Wb2,
                                           loss_slot, bcur);
  // CSR build stage A: LDS-binned bucket scatter
  binA_k<<<g_binA, blk, 0, stream>>>(ei, bcur, ebuf);
  // Fused: gemm1 (m1 -> uA, xr -> uC) || binB (esrc+rowptr) — independent
  binB_gemm1_k<<<g_fuse, blk, 0, stream>>>(x, Wb1, b1l, uA, uC,
                                           ebuf, bcur, esrc, rowptr);
  agg1_k<<<g_node, blk, 0, stream>>>(rowptr, esrc, uA, uC, uB);
  // Layer 2 (MFMA, bf16 input): m2 -> uA, hr -> uC (bf16)
  gemm2_k<<<g_tile, blk, 0, stream>>>(uB, Wb2, b2l, uA, uC);
  agg2_k<<<g_node, blk, 0, stream>>>(rowptr, esrc, uA, uC, out, uB);
  // Decode + loss (thread-per-edge, LDS dst window, rowptr binary search)
  decode_lds_k<<<g_dec, blk, 0, stream>>>(rowptr, esrc, uB, loss_slot);
}